// Round 5
// baseline (432.438 us; speedup 1.0000x reference)
//
#include <hip/hip_runtime.h>

// LSTM B=4096 T=336 I=21 H=50 OUT=24, fp32 in/out. MFMA bf16 2-limb.
// Round 5: 256 wgs x 448 thr = 7 waves; wave w owns M-tiles {2w, 2w+1}
// (tile 13 is zero-pad, skipped). B-fragment LDS reads are shared across a
// wave's 2 tiles -> per-CU LDS read traffic halves vs round 4 (42 vs 78
// b128/step). Conflict-free layout [buf][limb][kblock][batch16][8]:
//   kblock 0..7  = h (k 0..63, units 0..49 valid, rest zero)
//   kblock 8..11 = x (k 64..95, i = k-64 < 21 valid, rest zero)
// B-frag read address = const + lane*16B (contiguous, conflict-free).
// Packed gate row = unit*4 + gate -> lane's 4 acc regs = 4 gates of one unit:
// pointwise LSTM update fully in registers. One barrier per step.

#define T_SEQ 336
#define I_IN  21
#define HID   50
#define O_OUT 24
#define MB    16
#define NT    448
#define NTILE 13
#define KB    12

#define AIDX(buf, limb, kb, n, j) (((((buf)*2 + (limb))*KB + (kb))*16 + (n))*8 + (j))

typedef short bf16x8 __attribute__((ext_vector_type(8)));
typedef float f32x4  __attribute__((ext_vector_type(4)));

// round-to-nearest bf16 (weights, once)
static __device__ __forceinline__ unsigned short f2bf(float f) {
    unsigned u = __builtin_bit_cast(unsigned, f);
    return (unsigned short)((u + 0x7FFFu + ((u >> 16) & 1u)) >> 16);
}
static __device__ __forceinline__ float bf2f(unsigned short s) {
    unsigned u = ((unsigned)s) << 16;
    return __builtin_bit_cast(float, u);
}
// truncation 2-limb split (per-step path): err ~2^-16 rel
static __device__ __forceinline__ void split2(float v, short& hi, short& lo) {
    const unsigned u = __builtin_bit_cast(unsigned, v);
    hi = (short)(u >> 16);
    const float hf = __builtin_bit_cast(float, u & 0xFFFF0000u);
    const float l  = v - hf;
    lo = (short)(__builtin_bit_cast(unsigned, l) >> 16);
}
static __device__ __forceinline__ float frcp(float v) { return __builtin_amdgcn_rcpf(v); }
static __device__ __forceinline__ float sigm(float v) { return frcp(1.f + __expf(-v)); }
// tanh(v) = 1 - 2/(1+e^{2v}); exp overflow -> inf -> rcp -> 0 -> +1 (correct)
static __device__ __forceinline__ float tanh_f(float v) {
    return __builtin_fmaf(-2.f, frcp(1.f + __expf(2.f * v)), 1.f);
}

__global__ __launch_bounds__(NT)
void lstm_mfma5(const float* __restrict__ x,
                const float* __restrict__ W_ih,
                const float* __restrict__ W_hh,
                const float* __restrict__ b_ih,
                const float* __restrict__ b_hh,
                const float* __restrict__ W_fc,
                const float* __restrict__ b_fc,
                float* __restrict__ out)
{
    __shared__ short sAct[2 * 2 * KB * 16 * 8];   // 6144 shorts = 12 KB

    const int tid  = threadIdx.x;
    const int lane = tid & 63;
    const int wv   = tid >> 6;        // 0..6
    const int nl   = lane & 15;       // A: row-in-tile / B: batch col
    const int q    = lane >> 4;       // quad
    const int b0   = blockIdx.x * MB;

    // ---- zero-init LDS (pads must stay 0 forever; h(0)=0) ----
    for (int i = tid; i < 2 * 2 * KB * 16 * 8; i += NT) sAct[i] = 0;

    // ---- A (weight) fragments + bias for 2 tiles, built once ----
    const bool t1ok = (2 * wv + 1) < NTILE;    // wave 6's 2nd tile is pad
    bf16x8 Wh[2][3], Wl[2][3];
    f32x4  biasv[2];
    #pragma unroll
    for (int tt = 0; tt < 2; ++tt) {
        const int tile = 2 * wv + tt;
        const int p    = tile * 16 + nl;          // packed row
        const int unit = p >> 2, gate = p & 3;
        const bool vr  = (unit < HID) && (tile < NTILE);
        const int orig = gate * HID + unit;       // i,f,g,o stacked row
        const int ub   = tile * 4 + q;            // unit for D rows q*4+r
        #pragma unroll
        for (int r = 0; r < 4; ++r)
            biasv[tt][r] = (ub < HID) ? (b_ih[r * HID + ub] + b_hh[r * HID + ub]) : 0.f;
        #pragma unroll
        for (int kc = 0; kc < 3; ++kc) {
            #pragma unroll
            for (int j = 0; j < 8; ++j) {
                const int k = kc * 32 + q * 8 + j;
                float w = 0.f;
                if (vr) {
                    if (k < 64) { if (k < HID) w = W_hh[orig * HID + k]; }
                    else { const int ki = k - 64; if (ki < I_IN) w = W_ih[orig * I_IN + ki]; }
                }
                const unsigned short hi = f2bf(w);
                const unsigned short lo = f2bf(w - bf2f(hi));
                Wh[tt][kc][j] = (short)hi;
                Wl[tt][kc][j] = (short)lo;
            }
        }
    }

    __syncthreads();   // zero-init visible before x(0) staging

    // ---- x staging role: threads 0..335, one (b,i) each ----
    const bool stg = tid < MB * I_IN;
    const int  sb  = stg ? tid / I_IN : 0;
    const int  sk  = stg ? tid % I_IN : 0;
    const float* xg = x + (size_t)(b0 + sb) * T_SEQ * I_IN + sk;
    if (stg) {
        short hi, lo;
        split2(xg[0], hi, lo);
        sAct[AIDX(0, 0, 8 + (sk >> 3), sb, sk & 7)] = hi;
        sAct[AIDX(0, 1, 8 + (sk >> 3), sb, sk & 7)] = lo;
    }

    // pointwise: lane owns units 8wv+q (tt=0) and 8wv+4+q (tt=1), batch nl
    const int  uown[2] = {8 * wv + q, 8 * wv + 4 + q};
    const bool uval[2] = {uown[0] < HID, uown[1] < HID && t1ok};
    float cst[2] = {0.f, 0.f};

    for (int t = 0; t < T_SEQ; ++t) {
        const int cur = t & 1, nxt = cur ^ 1;

        // prefetch x(t+1) from global (committed after B-frag loads)
        float pf = 0.f;
        const bool do_pf = stg && (t + 1 < T_SEQ);
        if (do_pf) pf = xg[(size_t)(t + 1) * I_IN];

        __syncthreads();   // sAct[cur] (h(t) + x(t)) complete

        // ---- B (activation) fragments: 6 contiguous b128 reads ----
        bf16x8 Bh[3], Bl[3];
        #pragma unroll
        for (int kc = 0; kc < 3; ++kc) {
            const int kb = kc * 4 + q;
            Bh[kc] = *(const bf16x8*)&sAct[AIDX(cur, 0, kb, nl, 0)];
            Bl[kc] = *(const bf16x8*)&sAct[AIDX(cur, 1, kb, nl, 0)];
        }

        // commit prefetched x(t+1) early (overlaps MFMA)
        if (do_pf) {
            short hi, lo;
            split2(pf, hi, lo);
            sAct[AIDX(nxt, 0, 8 + (sk >> 3), sb, sk & 7)] = hi;
            sAct[AIDX(nxt, 1, 8 + (sk >> 3), sb, sk & 7)] = lo;
        }

        // ---- MFMA: 4 independent chains (aA/aB x 2 tiles) ----
        f32x4 aA0 = biasv[0], aB0 = {0.f, 0.f, 0.f, 0.f};
        f32x4 aA1 = biasv[1], aB1 = {0.f, 0.f, 0.f, 0.f};
        #pragma unroll
        for (int kc = 0; kc < 3; ++kc) {
            aA0 = __builtin_amdgcn_mfma_f32_16x16x32_bf16(Wh[0][kc], Bh[kc], aA0, 0, 0, 0);
            if (t1ok)
                aA1 = __builtin_amdgcn_mfma_f32_16x16x32_bf16(Wh[1][kc], Bh[kc], aA1, 0, 0, 0);
            aB0 = __builtin_amdgcn_mfma_f32_16x16x32_bf16(Wh[0][kc], Bl[kc], aB0, 0, 0, 0);
            if (t1ok)
                aB1 = __builtin_amdgcn_mfma_f32_16x16x32_bf16(Wh[1][kc], Bl[kc], aB1, 0, 0, 0);
            aA0 = __builtin_amdgcn_mfma_f32_16x16x32_bf16(Wl[0][kc], Bh[kc], aA0, 0, 0, 0);
            if (t1ok)
                aA1 = __builtin_amdgcn_mfma_f32_16x16x32_bf16(Wl[1][kc], Bh[kc], aA1, 0, 0, 0);
        }

        // ---- pointwise cell update, fully in registers ----
        #pragma unroll
        for (int tt = 0; tt < 2; ++tt) {
            if (uval[tt]) {
                const f32x4& aA = (tt == 0) ? aA0 : aA1;
                const f32x4& aB = (tt == 0) ? aB0 : aB1;
                const float gi = aA[0] + aB[0];
                const float gf = aA[1] + aB[1];
                const float gg = aA[2] + aB[2];
                const float go = aA[3] + aB[3];
                float c = cst[tt];
                c = __builtin_fmaf(sigm(gf), c, sigm(gi) * tanh_f(gg));
                cst[tt] = c;
                const float h = sigm(go) * tanh_f(c);
                short hi, lo;
                split2(h, hi, lo);
                const int u = uown[tt];
                sAct[AIDX(nxt, 0, u >> 3, nl, u & 7)] = hi;
                sAct[AIDX(nxt, 1, u >> 3, nl, u & 7)] = lo;
            }
        }
    }

    __syncthreads();
    // final h: t=335 wrote buf 0
    // ---- FC epilogue: 16*24 = 384 tasks (one-time) ----
    if (tid < MB * O_OUT) {
        const int b = tid / O_OUT, o = tid % O_OUT;
        float a = b_fc[o];
        for (int u = 0; u < HID; ++u) {
            const float hv = bf2f((unsigned short)sAct[AIDX(0, 0, u >> 3, b, u & 7)])
                           + bf2f((unsigned short)sAct[AIDX(0, 1, u >> 3, b, u & 7)]);
            a = __builtin_fmaf(hv, W_fc[o * HID + u], a);
        }
        out[(size_t)(b0 + b) * O_OUT + o] = a;
    }
}

extern "C" void kernel_launch(void* const* d_in, const int* in_sizes, int n_in,
                              void* d_out, int out_size, void* d_ws, size_t ws_size,
                              hipStream_t stream)
{
    const float* x    = (const float*)d_in[0];
    const float* W_ih = (const float*)d_in[1];
    const float* W_hh = (const float*)d_in[2];
    const float* b_ih = (const float*)d_in[3];
    const float* b_hh = (const float*)d_in[4];
    const float* W_fc = (const float*)d_in[5];
    const float* b_fc = (const float*)d_in[6];
    float* out = (float*)d_out;

    lstm_mfma5<<<dim3(4096 / MB), dim3(NT), 0, stream>>>(
        x, W_ih, W_hh, b_ih, b_hh, W_fc, b_fc, out);
}

// Round 6
// 408.882 us; speedup vs baseline: 1.0576x; 1.0576x over previous
//
#include <hip/hip_runtime.h>

// LSTM B=4096 T=336 I=21 H=50 OUT=24, fp32 in/out.
// Round 6: R4 parallel structure (256 wgs x 832 thr = 13 waves, one 16-row
// M-tile per wave, one barrier per step) + fp16 numerics:
//   activations (h, x) stored as SINGLE fp16 limbs in LDS (err 2^-11),
//   weights as TWO fp16 limbs resident in VGPRs (err 2^-22, free),
//   gates = Wh.B + Wl.B  -> 2 MFMA products, 3 b128 B-frag reads per wave
//   (vs round 4's 9 products / 6 reads with bf16 2-limb activations).
// Conflict-free LDS layout [buf][kblock][batch16][8] (halves):
//   kblock 0..7  = h (k 0..63, units 0..49 valid, rest zero)
//   kblock 8..11 = x (k 64..95, i = k-64 < 21 valid, rest zero)
// B-frag read address = const + lane*16B (contiguous, conflict-free).
// Packed gate row = unit*4 + gate -> lane's 4 acc regs = 4 gates of one unit:
// pointwise LSTM update fully in registers.

#define T_SEQ 336
#define I_IN  21
#define HID   50
#define O_OUT 24
#define MB    16
#define NT    832
#define NTILE 13
#define KB    12

#define AIDX(buf, kb, n, j) ((((buf)*KB + (kb))*16 + (n))*8 + (j))

typedef _Float16 f16x8 __attribute__((ext_vector_type(8)));
typedef float    f32x4 __attribute__((ext_vector_type(4)));

static __device__ __forceinline__ float frcp(float v) { return __builtin_amdgcn_rcpf(v); }
static __device__ __forceinline__ float sigm(float v) { return frcp(1.f + __expf(-v)); }
// tanh(v) = 1 - 2/(1+e^{2v}); exp overflow -> inf -> rcp -> 0 -> +1 (correct)
static __device__ __forceinline__ float tanh_f(float v) {
    return __builtin_fmaf(-2.f, frcp(1.f + __expf(2.f * v)), 1.f);
}

__global__ __launch_bounds__(NT)
void lstm_mfma6(const float* __restrict__ x,
                const float* __restrict__ W_ih,
                const float* __restrict__ W_hh,
                const float* __restrict__ b_ih,
                const float* __restrict__ b_hh,
                const float* __restrict__ W_fc,
                const float* __restrict__ b_fc,
                float* __restrict__ out)
{
    __shared__ _Float16 sAct[2 * KB * 16 * 8];   // 3072 halves = 6 KB

    const int tid  = threadIdx.x;
    const int lane = tid & 63;
    const int wv   = tid >> 6;        // 0..12 == M-tile
    const int nl   = lane & 15;       // A: row-in-tile / B: batch col
    const int q    = lane >> 4;       // quad
    const int b0   = blockIdx.x * MB;

    // ---- zero-init LDS (pads must stay 0 forever; h(0)=0) ----
    for (int i = tid; i < 2 * KB * 16 * 8; i += NT) sAct[i] = (_Float16)0.f;

    // ---- A (weight) 2-limb fp16 fragments + bias, built once ----
    // A[m=nl][k = kc*32 + q*8 + j]; packed row p = wv*16+nl -> unit=p>>2, gate=p&3
    f16x8 Wh[3], Wl[3];
    f32x4 biasv;
    {
        const int p    = wv * 16 + nl;
        const int unit = p >> 2, gate = p & 3;
        const bool vr  = (unit < HID);
        const int orig = gate * HID + unit;       // i,f,g,o stacked row
        const int ub   = wv * 4 + q;              // unit for D rows q*4+r
        #pragma unroll
        for (int r = 0; r < 4; ++r)
            biasv[r] = (ub < HID) ? (b_ih[r * HID + ub] + b_hh[r * HID + ub]) : 0.f;
        #pragma unroll
        for (int kc = 0; kc < 3; ++kc) {
            #pragma unroll
            for (int j = 0; j < 8; ++j) {
                const int k = kc * 32 + q * 8 + j;
                float w = 0.f;
                if (vr) {
                    if (k < 64) { if (k < HID) w = W_hh[orig * HID + k]; }
                    else { const int ki = k - 64; if (ki < I_IN) w = W_ih[orig * I_IN + ki]; }
                }
                const _Float16 hi = (_Float16)w;
                const _Float16 lo = (_Float16)(w - (float)hi);
                Wh[kc][j] = hi;
                Wl[kc][j] = lo;
            }
        }
    }

    __syncthreads();   // zero-init visible before x(0) staging

    // ---- x staging role: threads 0..335, one (b,i) each ----
    const bool stg = tid < MB * I_IN;
    const int  sb  = stg ? tid / I_IN : 0;
    const int  sk  = stg ? tid % I_IN : 0;
    const float* xg = x + (size_t)(b0 + sb) * T_SEQ * I_IN + sk;
    const int  xoff = AIDX(0, 8 + (sk >> 3), sb, sk & 7);   // buf stride added below
    if (stg) sAct[xoff] = (_Float16)xg[0];

    // pointwise: lane owns unit uown = 4wv+q for batch nl (c in register)
    const int  uown = wv * 4 + q;
    const bool uval = (uown < HID);
    const int  hoff = AIDX(0, uown >> 3, nl, uown & 7);
    float cst = 0.f;

    // hoisted B-frag base pointers for both buffers
    const _Float16* bbase0 = &sAct[AIDX(0, q, nl, 0)];
    const _Float16* bbase1 = &sAct[AIDX(1, q, nl, 0)];
    const int BUFS = KB * 16 * 8;     // halves per buffer

    for (int t = 0; t < T_SEQ; ++t) {
        const int cur = t & 1, nxt = cur ^ 1;

        // prefetch x(t+1) from global (committed after B-frag loads)
        float pf = 0.f;
        const bool do_pf = stg && (t + 1 < T_SEQ);
        if (do_pf) pf = xg[(size_t)(t + 1) * I_IN];

        __syncthreads();   // sAct[cur] (h(t) + x(t)) complete

        // ---- B (activation) fragments: 3 contiguous b128 reads ----
        const _Float16* bb = cur ? bbase1 : bbase0;
        f16x8 B0 = *(const f16x8*)(bb);
        f16x8 B1 = *(const f16x8*)(bb + 4 * 16 * 8);
        f16x8 B2 = *(const f16x8*)(bb + 8 * 16 * 8);

        // commit prefetched x(t+1) early (overlaps MFMA)
        if (do_pf) sAct[nxt * BUFS + xoff] = (_Float16)pf;

        // ---- MFMA: two independent 3-deep chains ----
        f32x4 aA = biasv;
        f32x4 aB = {0.f, 0.f, 0.f, 0.f};
        aA = __builtin_amdgcn_mfma_f32_16x16x32_f16(Wh[0], B0, aA, 0, 0, 0);
        aB = __builtin_amdgcn_mfma_f32_16x16x32_f16(Wl[0], B0, aB, 0, 0, 0);
        aA = __builtin_amdgcn_mfma_f32_16x16x32_f16(Wh[1], B1, aA, 0, 0, 0);
        aB = __builtin_amdgcn_mfma_f32_16x16x32_f16(Wl[1], B1, aB, 0, 0, 0);
        aA = __builtin_amdgcn_mfma_f32_16x16x32_f16(Wh[2], B2, aA, 0, 0, 0);
        aB = __builtin_amdgcn_mfma_f32_16x16x32_f16(Wl[2], B2, aB, 0, 0, 0);

        // ---- pointwise cell update, fully in registers ----
        if (uval) {
            const float gi = aA[0] + aB[0];
            const float gf = aA[1] + aB[1];
            const float gg = aA[2] + aB[2];
            const float go = aA[3] + aB[3];
            float c = cst;
            c = __builtin_fmaf(sigm(gf), c, sigm(gi) * tanh_f(gg));
            cst = c;
            const float h = sigm(go) * tanh_f(c);
            sAct[nxt * BUFS + hoff] = (_Float16)h;
        }
    }

    __syncthreads();
    // final h: t=335 wrote buf 0
    // ---- FC epilogue: 16*24 = 384 tasks (one-time) ----
    if (tid < MB * O_OUT) {
        const int b = tid / O_OUT, o = tid % O_OUT;
        float a = b_fc[o];
        for (int u = 0; u < HID; ++u) {
            const float hv = (float)sAct[AIDX(0, u >> 3, b, u & 7)];
            a = __builtin_fmaf(hv, W_fc[o * HID + u], a);
        }
        out[(size_t)(b0 + b) * O_OUT + o] = a;
    }
}

extern "C" void kernel_launch(void* const* d_in, const int* in_sizes, int n_in,
                              void* d_out, int out_size, void* d_ws, size_t ws_size,
                              hipStream_t stream)
{
    const float* x    = (const float*)d_in[0];
    const float* W_ih = (const float*)d_in[1];
    const float* W_hh = (const float*)d_in[2];
    const float* b_ih = (const float*)d_in[3];
    const float* b_hh = (const float*)d_in[4];
    const float* W_fc = (const float*)d_in[5];
    const float* b_fc = (const float*)d_in[6];
    float* out = (float*)d_out;

    lstm_mfma6<<<dim3(4096 / MB), dim3(NT), 0, stream>>>(
        x, W_ih, W_hh, b_ih, b_hh, W_fc, b_fc, out);
}